// Round 5
// baseline (425.658 us; speedup 1.0000x reference)
//
#include <hip/hip_runtime.h>

#define HH 2000
#define WW 1000
#define HWSZ (HH * WW)
#define NEG_INF (-3.0e38f)

// ---- monotone float<->uint encoding for atomicMax on floats ----
__device__ __forceinline__ unsigned fenc(float f) {
    unsigned u = __float_as_uint(f);
    return (u & 0x80000000u) ? ~u : (u | 0x80000000u);
}
__device__ __forceinline__ float fdec(unsigned k) {
    unsigned u = (k & 0x80000000u) ? (k & 0x7fffffffu) : ~k;
    return __uint_as_float(u);
}

__global__ void init_buckets(unsigned* __restrict__ buck, int n) {
    int i = blockIdx.x * blockDim.x + threadIdx.x;
    if (i < n) buck[i] = 0u;  // 0 < enc(x) for every real float x
}

__global__ void decode_buckets(unsigned* __restrict__ buck, int n) {
    int i = blockIdx.x * blockDim.x + threadIdx.x;
    if (i < n) {
        unsigned k = buck[i];
        ((float*)buck)[i] = fdec(k);
    }
}

// Fully-unrolled dense layer + ReLU applied to TWO pixels per thread:
// each s_loaded weight feeds 2 FMAs.
template <int C, int O>
__device__ __forceinline__ void layer_pair_relu(const float* __restrict__ w,
                                                const float* __restrict__ b,
                                                const float* __restrict__ x0,
                                                const float* __restrict__ x1,
                                                float* __restrict__ y0,
                                                float* __restrict__ y1) {
#pragma unroll
    for (int o = 0; o < O; ++o) {
        float a0 = b[o];
        float a1 = a0;
#pragma unroll
        for (int c = 0; c < C; ++c) {
            float wv = w[o * C + c];
            a0 = fmaf(wv, x0[c], a0);
            a1 = fmaf(wv, x1[c], a1);
        }
        y0[o] = fmaxf(a0, 0.0f);
        y1[o] = fmaxf(a1, 0.0f);
    }
}

// amdgpu_waves_per_eu(2,2): pin the backend's occupancy TARGET to 2 waves/EU
// so the register budget is 256 VGPRs and the allocator stops shuffling the
// live set through AGPRs (v_accvgpr_*) / scratch to chase 6 waves. R2-R4's
// 4.6x VALU-instruction bloat at flat WRITE_SIZE was exactly that shuffle.
__global__ void __launch_bounds__(256)
    __attribute__((amdgpu_waves_per_eu(2, 2))) mlp_max_kernel(
    const float* __restrict__ in,
    const float* __restrict__ w1, const float* __restrict__ b1,
    const float* __restrict__ w2, const float* __restrict__ b2,
    const float* __restrict__ w3, const float* __restrict__ b3,
    const float* __restrict__ w4, const float* __restrict__ b4,
    unsigned* __restrict__ rowbuck, unsigned* __restrict__ colbuck) {
    __shared__ float cred[4][64];

    const int tx = threadIdx.x;           // 0..63 (lane)
    const int ty = threadIdx.y;           // 0..3  (wave id)

    const int col = blockIdx.x * 64 + tx;   // 0..1023 (>=1000 masked)
    const int rb = blockIdx.y * 16;         // block covers rows rb..rb+15
    const bool colok = (col < WW);

    float colmax = NEG_INF;

#pragma unroll 1
    for (int kk = 0; kk < 2; ++kk) {
        const int r0 = rb + kk * 8 + ty;    // wave-uniform rows, always < HH
        const int r1 = r0 + 4;
        const int p0 = colok ? (r0 * WW + col) : (r0 * WW);
        const int p1 = colok ? (r1 * WW + col) : (r1 * WW);

        float xa0[36], xa1[36], ya0[18], ya1[18];
#pragma unroll
        for (int c = 0; c < 9; ++c) {
            xa0[c] = in[c * HWSZ + p0];     // coalesced across lanes
            xa1[c] = in[c * HWSZ + p1];
        }

        layer_pair_relu<9, 18>(w1, b1, xa0, xa1, ya0, ya1);   // -> 18x2
        layer_pair_relu<18, 36>(w2, b2, ya0, ya1, xa0, xa1);  // -> 36x2

        // layer 3 fused with layer 4: never materialize the 36-wide L3 output
        float s0 = b4[0];
        float s1 = s0;
#pragma unroll
        for (int o = 0; o < 36; ++o) {
            float bo = b3[o];
            float a0 = bo, a1 = bo;
#pragma unroll
            for (int c = 0; c < 36; ++c) {
                float wv = w3[o * 36 + c];
                a0 = fmaf(wv, xa0[c], a0);
                a1 = fmaf(wv, xa1[c], a1);
            }
            float w4o = w4[o];
            s0 = fmaf(w4o, fmaxf(a0, 0.0f), s0);
            s1 = fmaf(w4o, fmaxf(a1, 0.0f), s1);
        }

        s0 = colok ? s0 : NEG_INF;
        s1 = colok ? s1 : NEG_INF;
        colmax = fmaxf(colmax, fmaxf(s0, s1));

        // row max: all 64 lanes of this wave share rows r0, r1
        float m0 = s0, m1 = s1;
#pragma unroll
        for (int off = 32; off > 0; off >>= 1) {
            m0 = fmaxf(m0, __shfl_xor(m0, off, 64));
            m1 = fmaxf(m1, __shfl_xor(m1, off, 64));
        }
        if (tx == 0) {
            atomicMax(&rowbuck[r0], fenc(m0));
            atomicMax(&rowbuck[r1], fenc(m1));
        }
    }

    // col max: reduce the 4 waves' per-column maxima through LDS
    cred[ty][tx] = colmax;
    __syncthreads();
    if (ty == 0 && colok) {
        float m = fmaxf(fmaxf(cred[0][tx], cred[1][tx]),
                        fmaxf(cred[2][tx], cred[3][tx]));
        atomicMax(&colbuck[col], fenc(m));
    }
}

extern "C" void kernel_launch(void* const* d_in, const int* in_sizes, int n_in,
                              void* d_out, int out_size, void* d_ws, size_t ws_size,
                              hipStream_t stream) {
    const float* in = (const float*)d_in[0];
    // d_in[1] = T_out (unused), d_in[2] = T_indices (identity, unused)
    const float* w1 = (const float*)d_in[3];
    const float* b1 = (const float*)d_in[4];
    const float* w2 = (const float*)d_in[5];
    const float* b2 = (const float*)d_in[6];
    const float* w3 = (const float*)d_in[7];
    const float* b3 = (const float*)d_in[8];
    const float* w4 = (const float*)d_in[9];
    const float* b4 = (const float*)d_in[10];

    unsigned* buck = (unsigned*)d_out;  // [0,2000) row maxes, [2000,3000) col maxes

    init_buckets<<<(3000 + 255) / 256, 256, 0, stream>>>(buck, 3000);

    dim3 block(64, 4);
    dim3 grid(16, 125);  // 16*64=1024 >= 1000 cols ; 125*16=2000 rows exactly
    mlp_max_kernel<<<grid, block, 0, stream>>>(in, w1, b1, w2, b2, w3, b3, w4, b4,
                                               buck, buck + 2000);

    decode_buckets<<<(3000 + 255) / 256, 256, 0, stream>>>(buck, 3000);
}

// Round 6
// 321.962 us; speedup vs baseline: 1.3221x; 1.3221x over previous
//
#include <hip/hip_runtime.h>

typedef _Float16 f16x8 __attribute__((ext_vector_type(8)));
typedef _Float16 f16x4 __attribute__((ext_vector_type(4)));
typedef float f32x4 __attribute__((ext_vector_type(4)));

#define HH 2000
#define WW 1000
#define HWSZ (HH * WW)
#define NEG_INF (-3.0e38f)

// ---- monotone float<->uint encoding for atomicMax on floats ----
__device__ __forceinline__ unsigned fenc(float f) {
    unsigned u = __float_as_uint(f);
    return (u & 0x80000000u) ? ~u : (u | 0x80000000u);
}
__device__ __forceinline__ float fdec(unsigned k) {
    unsigned u = (k & 0x80000000u) ? (k & 0x7fffffffu) : ~k;
    return __uint_as_float(u);
}

__global__ void init_buckets(unsigned* __restrict__ buck, int n) {
    int i = blockIdx.x * blockDim.x + threadIdx.x;
    if (i < n) buck[i] = 0u;
}

__global__ void decode_buckets(unsigned* __restrict__ buck, int n) {
    int i = blockIdx.x * blockDim.x + threadIdx.x;
    if (i < n) {
        unsigned k = buck[i];
        ((float*)buck)[i] = fdec(k);
    }
}

// MFMA 16x16x32 f16 layouts (gfx950, HW-verified per guide):
//   A: lane holds A[m=lane&15][k=(lane>>4)*8 + j], j=0..7
//   B: lane holds B[k=(lane>>4)*8 + j][n=lane&15]
//   C/D: lane holds D[row=(lane>>4)*4 + reg][col=lane&15]
// Here: A = weights (m = out-channel), B = activations (n = pixel).

__global__ __launch_bounds__(256, 1) void mlp_max_mfma(
    const float* __restrict__ in,
    const float* __restrict__ w1, const float* __restrict__ b1,
    const float* __restrict__ w2, const float* __restrict__ b2,
    const float* __restrict__ w3, const float* __restrict__ b3,
    const float* __restrict__ w4, const float* __restrict__ b4,
    unsigned* __restrict__ rowbuck, unsigned* __restrict__ colbuck) {
    // per-wave activation staging: buf1 = [16 px][40 halves] (K=32 + pad),
    // buf2 = [16 px][72 halves] (K=64 + pad). Strides 40/72 halves keep every
    // b128 16B-aligned (80B,144B both %16==0) and hit the 8-lane/window floor.
    __shared__ _Float16 lds[4][16 * 40 + 16 * 72];

    const int tx = threadIdx.x;       // 0..63 lane
    const int wv = threadIdx.y;       // 0..3 wave
    const int px = tx & 15;
    const int q = tx >> 4;            // quad 0..3

    _Float16* buf1 = &lds[wv][0];
    _Float16* buf2 = &lds[wv][640];

    // zero own wave's LDS slice once (buf2 ch 48..63 pad must be 0)
    {
        unsigned* z = (unsigned*)&lds[wv][0];
        for (int i = tx; i < 896; i += 64) z[i] = 0u;
    }

    // ---- load weight A-fragments (once per wave, reused for all pixels) ----
    f16x8 A1[2], A2[3], A3[3][2];
#pragma unroll
    for (int t = 0; t < 2; ++t) {
        const int m = t * 16 + px;
#pragma unroll
        for (int j = 0; j < 8; ++j) {
            const int k = q * 8 + j;
            float v = 0.f;
            if (m < 18 && k < 9) v = w1[m * 9 + k];
            A1[t][j] = (_Float16)v;
        }
    }
#pragma unroll
    for (int t = 0; t < 3; ++t) {
        const int m = t * 16 + px;
#pragma unroll
        for (int j = 0; j < 8; ++j) {
            const int k = q * 8 + j;
            float v = 0.f;
            if (m < 36 && k < 18) v = w2[m * 18 + k];
            A2[t][j] = (_Float16)v;
        }
    }
#pragma unroll
    for (int t = 0; t < 3; ++t) {
        const int m = t * 16 + px;
#pragma unroll
        for (int s = 0; s < 2; ++s) {
#pragma unroll
            for (int j = 0; j < 8; ++j) {
                const int k = s * 32 + q * 8 + j;
                float v = 0.f;
                if (m < 36 && k < 36) v = w3[m * 36 + k];
                A3[t][s][j] = (_Float16)v;
            }
        }
    }

    // per-lane biases / w4 for the channels this lane's D-regs hold
    float b1r[2][4], b2r[3][4], b3r[3][4], w4r[3][4];
#pragma unroll
    for (int t = 0; t < 2; ++t)
#pragma unroll
        for (int rg = 0; rg < 4; ++rg) {
            const int ch = t * 16 + q * 4 + rg;
            b1r[t][rg] = (ch < 18) ? b1[ch] : 0.f;
        }
#pragma unroll
    for (int t = 0; t < 3; ++t)
#pragma unroll
        for (int rg = 0; rg < 4; ++rg) {
            const int ch = t * 16 + q * 4 + rg;
            b2r[t][rg] = (ch < 36) ? b2[ch] : 0.f;
            b3r[t][rg] = (ch < 36) ? b3[ch] : 0.f;
            w4r[t][rg] = (ch < 36) ? w4[ch] : 0.f;
        }
    const float b4s = b4[0];

    const int col = blockIdx.x * 64 + wv * 16 + px;  // this lane's pixel column
    const int colc = (col < WW) ? col : (WW - 1);
    const bool colok = (col < WW);
    const int rb = blockIdx.y * 25;

    float colmax = NEG_INF;
    const f32x4 zf4 = {0.f, 0.f, 0.f, 0.f};

#pragma unroll 1
    for (int rr = 0; rr < 25; ++rr) {
        const int r = rb + rr;

        // ---- input B-fragment (K=32: ch 0..8 real, rest zero) ----
        f16x8 bin;
#pragma unroll
        for (int j = 0; j < 8; ++j) {
            const int c = q * 8 + j;
            float v = 0.f;
            if (c < 9) v = in[c * HWSZ + r * WW + colc];
            bin[j] = (_Float16)v;
        }

        // ---- layer 1 ----
        f32x4 D1[2];
#pragma unroll
        for (int t = 0; t < 2; ++t)
            D1[t] = __builtin_amdgcn_mfma_f32_16x16x32_f16(A1[t], bin, zf4, 0, 0, 0);

#pragma unroll
        for (int t = 0; t < 2; ++t) {
            f16x4 hv;
#pragma unroll
            for (int rg = 0; rg < 4; ++rg)
                hv[rg] = (_Float16)fmaxf(D1[t][rg] + b1r[t][rg], 0.f);
            *(f16x4*)&buf1[px * 40 + t * 16 + q * 4] = hv;  // ds_write_b64
        }
        const f16x8 b2f = *(f16x8*)&buf1[px * 40 + q * 8];  // ds_read_b128

        // ---- layer 2 ----
        f32x4 D2[3];
#pragma unroll
        for (int t = 0; t < 3; ++t)
            D2[t] = __builtin_amdgcn_mfma_f32_16x16x32_f16(A2[t], b2f, zf4, 0, 0, 0);

#pragma unroll
        for (int t = 0; t < 3; ++t) {
            f16x4 hv;
#pragma unroll
            for (int rg = 0; rg < 4; ++rg)
                hv[rg] = (_Float16)fmaxf(D2[t][rg] + b2r[t][rg], 0.f);
            *(f16x4*)&buf2[px * 72 + t * 16 + q * 4] = hv;  // ds_write_b64
        }
        const f16x8 b3f0 = *(f16x8*)&buf2[px * 72 + q * 8];       // k 0..31
        const f16x8 b3f1 = *(f16x8*)&buf2[px * 72 + 32 + q * 8];  // k 32..63 (48+ pre-zeroed)

        // ---- layer 3 (two K-slices) ----
        f32x4 D3[3];
#pragma unroll
        for (int t = 0; t < 3; ++t) {
            D3[t] = __builtin_amdgcn_mfma_f32_16x16x32_f16(A3[t][0], b3f0, zf4, 0, 0, 0);
            D3[t] = __builtin_amdgcn_mfma_f32_16x16x32_f16(A3[t][1], b3f1, D3[t], 0, 0, 0);
        }

        // ---- layer 4 fused epilogue: s = sum_ch w4[ch]*relu(x3[ch]) ----
        float s = 0.f;
#pragma unroll
        for (int t = 0; t < 3; ++t)
#pragma unroll
            for (int rg = 0; rg < 4; ++rg)
                s = fmaf(w4r[t][rg], fmaxf(D3[t][rg] + b3r[t][rg], 0.f), s);
        // reduce partials across the 4 quads (same px)
        s += __shfl_xor(s, 16, 64);
        s += __shfl_xor(s, 32, 64);
        s += b4s;

        s = colok ? s : NEG_INF;
        colmax = fmaxf(colmax, s);

        // row max over this wave's 16 px (each quad reduces identically)
        float m = s;
        m = fmaxf(m, __shfl_xor(m, 1, 64));
        m = fmaxf(m, __shfl_xor(m, 2, 64));
        m = fmaxf(m, __shfl_xor(m, 4, 64));
        m = fmaxf(m, __shfl_xor(m, 8, 64));
        if (tx == 0) atomicMax(&rowbuck[r], fenc(m));
    }

    if (q == 0 && colok) atomicMax(&colbuck[col], fenc(colmax));
}

extern "C" void kernel_launch(void* const* d_in, const int* in_sizes, int n_in,
                              void* d_out, int out_size, void* d_ws, size_t ws_size,
                              hipStream_t stream) {
    const float* in = (const float*)d_in[0];
    // d_in[1] = T_out (unused), d_in[2] = T_indices (identity, unused)
    const float* w1 = (const float*)d_in[3];
    const float* b1 = (const float*)d_in[4];
    const float* w2 = (const float*)d_in[5];
    const float* b2 = (const float*)d_in[6];
    const float* w3 = (const float*)d_in[7];
    const float* b3 = (const float*)d_in[8];
    const float* w4 = (const float*)d_in[9];
    const float* b4 = (const float*)d_in[10];

    unsigned* buck = (unsigned*)d_out;  // [0,2000) row maxes, [2000,3000) col maxes

    init_buckets<<<(3000 + 255) / 256, 256, 0, stream>>>(buck, 3000);

    dim3 block(64, 4);
    dim3 grid(16, 80);  // 16*64=1024 >= 1000 cols ; 80*25=2000 rows exactly
    mlp_max_mfma<<<grid, block, 0, stream>>>(in, w1, b1, w2, b2, w3, b3, w4, b4,
                                             buck, buck + 2000);

    decode_buckets<<<(3000 + 255) / 256, 256, 0, stream>>>(buck, 3000);
}

// Round 7
// 255.473 us; speedup vs baseline: 1.6662x; 1.2603x over previous
//
#include <hip/hip_runtime.h>

typedef _Float16 f16x8 __attribute__((ext_vector_type(8)));
typedef _Float16 f16x4 __attribute__((ext_vector_type(4)));
typedef float f32x4 __attribute__((ext_vector_type(4)));

#define HH 2000
#define WW 1000
#define HWSZ (HH * WW)
#define NEG_INF (-3.0e38f)

// ---- monotone float<->uint encoding for atomicMax on floats ----
__device__ __forceinline__ unsigned fenc(float f) {
    unsigned u = __float_as_uint(f);
    return (u & 0x80000000u) ? ~u : (u | 0x80000000u);
}
__device__ __forceinline__ float fdec(unsigned k) {
    unsigned u = (k & 0x80000000u) ? (k & 0x7fffffffu) : ~k;
    return __uint_as_float(u);
}

__global__ void init_buckets(unsigned* __restrict__ buck, int n) {
    int i = blockIdx.x * blockDim.x + threadIdx.x;
    if (i < n) buck[i] = 0u;
}

__global__ void decode_buckets(unsigned* __restrict__ buck, int n) {
    int i = blockIdx.x * blockDim.x + threadIdx.x;
    if (i < n) {
        unsigned k = buck[i];
        ((float*)buck)[i] = fdec(k);
    }
}

// MFMA 16x16x32 f16 layouts (gfx950, verified by R6 absmax=2e-3):
//   A: lane holds A[m=lane&15][k=(lane>>4)*8+j]
//   B: lane holds B[k=(lane>>4)*8+j][n=lane&15]
//   D: lane holds D[row=(lane>>4)*4+reg][col=lane&15]
// A = weights (m = out-ch), B = activations (n = pixel).
// Biases folded into MFMA via a constant-1 input channel (K 9->10, 18->19, 36->37).

__global__ __launch_bounds__(256, 1) void mlp_max_mfma(
    const float* __restrict__ in,
    const float* __restrict__ w1, const float* __restrict__ b1,
    const float* __restrict__ w2, const float* __restrict__ b2,
    const float* __restrict__ w3, const float* __restrict__ b3,
    const float* __restrict__ w4, const float* __restrict__ b4,
    unsigned* __restrict__ rowbuck, unsigned* __restrict__ colbuck) {
    // per wave: 2 row-slots x (buf1[16][40] + buf2[16][40]) halves.
    // stride 40 halves = 80B: every b128 16B-aligned. Every byte read is
    // written earlier in the same iteration -> no zero-init needed.
    __shared__ _Float16 lds[4][2 * 1280];

    const int tx = threadIdx.x;   // 0..63
    const int wv = threadIdx.y;   // 0..3
    const int px = tx & 15;
    const int q = tx >> 4;

    _Float16* s0buf1 = &lds[wv][0];
    _Float16* s0buf2 = &lds[wv][640];
    _Float16* s1buf1 = &lds[wv][1280];
    _Float16* s1buf2 = &lds[wv][1920];

    // ---- weight A-fragments (persistent, reused every iteration) ----
    f16x8 A1[2], A2[3], A3s0[3], A3s1[3];
#pragma unroll
    for (int t = 0; t < 2; ++t) {
        const int m = t * 16 + px;
#pragma unroll
        for (int j = 0; j < 8; ++j) {
            const int k = q * 8 + j;
            float v = 0.f;
            if (m < 18) {
                if (k < 9) v = w1[m * 9 + k];
                else if (k == 9) v = b1[m];
            }
            A1[t][j] = (_Float16)v;
        }
    }
#pragma unroll
    for (int t = 0; t < 3; ++t) {
        const int m = t * 16 + px;
#pragma unroll
        for (int j = 0; j < 8; ++j) {
            const int k = q * 8 + j;
            float v = 0.f;
            if (m < 36) {
                if (k < 18) v = w2[m * 18 + k];
                else if (k == 18) v = b2[m];
            }
            A2[t][j] = (_Float16)v;
        }
    }
#pragma unroll
    for (int t = 0; t < 3; ++t) {
        const int m = t * 16 + px;
#pragma unroll
        for (int j = 0; j < 8; ++j) {
            const int k = q * 8 + j;
            float v = 0.f;
            if (m < 36 && k < 32) v = w3[m * 36 + k];
            A3s0[t][j] = (_Float16)v;
            float v2 = 0.f;
            const int k2 = 32 + k;  // second K-slice: ch 32..35 real, 36 = bias
            if (m < 36) {
                if (k2 < 36) v2 = w3[m * 36 + k2];
                else if (k2 == 36) v2 = b3[m];
            }
            A3s1[t][j] = (_Float16)v2;
        }
    }

    float w4r[3][4];
#pragma unroll
    for (int t = 0; t < 3; ++t)
#pragma unroll
        for (int rg = 0; rg < 4; ++rg) {
            const int ch = t * 16 + q * 4 + rg;
            w4r[t][rg] = (ch < 36) ? w4[ch] : 0.f;
        }
    const float b4s = b4[0];

    const int col = blockIdx.x * 64 + wv * 16 + px;
    const int colc = (col < WW) ? col : (WW - 1);
    const bool colok = (col < WW);
    const int rb = blockIdx.y * 16;

    float colmax = NEG_INF;
    const f32x4 zf4 = {0.f, 0.f, 0.f, 0.f};

#pragma unroll 1
    for (int it = 0; it < 8; ++it) {
        const int r0 = rb + it * 2;
        const int r1 = r0 + 1;

        // ---- inputs, both rows (K=10: ch 0..8 + constant-1 bias channel) ----
        f16x8 bin0, bin1;
#pragma unroll
        for (int j = 0; j < 8; ++j) {
            const int c = q * 8 + j;
            float v0 = 0.f, v1 = 0.f;
            if (c < 9) {
                v0 = in[c * HWSZ + r0 * WW + colc];
                v1 = in[c * HWSZ + r1 * WW + colc];
            } else if (c == 9) {
                v0 = 1.f; v1 = 1.f;
            }
            bin0[j] = (_Float16)v0;
            bin1[j] = (_Float16)v1;
        }

        // ---- layer 1 (bias included via k=9) ----
        f32x4 D1a[2], D1b[2];
#pragma unroll
        for (int t = 0; t < 2; ++t) {
            D1a[t] = __builtin_amdgcn_mfma_f32_16x16x32_f16(A1[t], bin0, zf4, 0, 0, 0);
            D1b[t] = __builtin_amdgcn_mfma_f32_16x16x32_f16(A1[t], bin1, zf4, 0, 0, 0);
        }
#pragma unroll
        for (int t = 0; t < 2; ++t) {
            f16x4 h0, h1;
#pragma unroll
            for (int rg = 0; rg < 4; ++rg) {
                h0[rg] = (_Float16)fmaxf(D1a[t][rg], 0.f);
                h1[rg] = (_Float16)fmaxf(D1b[t][rg], 0.f);
            }
            if (t == 1 && q == 0) { h0[2] = (_Float16)1.f; h1[2] = (_Float16)1.f; }  // ch18 = 1
            *(f16x4*)&s0buf1[px * 40 + t * 16 + q * 4] = h0;
            *(f16x4*)&s1buf1[px * 40 + t * 16 + q * 4] = h1;
        }
        const f16x8 B2a = *(const f16x8*)&s0buf1[px * 40 + q * 8];
        const f16x8 B2b = *(const f16x8*)&s1buf1[px * 40 + q * 8];

        // ---- layer 2 (bias via k=18) ----
        f32x4 D2a[3], D2b[3];
#pragma unroll
        for (int t = 0; t < 3; ++t) {
            D2a[t] = __builtin_amdgcn_mfma_f32_16x16x32_f16(A2[t], B2a, zf4, 0, 0, 0);
            D2b[t] = __builtin_amdgcn_mfma_f32_16x16x32_f16(A2[t], B2b, zf4, 0, 0, 0);
        }
#pragma unroll
        for (int t = 0; t < 3; ++t) {
            f16x4 h0, h1;
#pragma unroll
            for (int rg = 0; rg < 4; ++rg) {
                h0[rg] = (_Float16)fmaxf(D2a[t][rg], 0.f);
                h1[rg] = (_Float16)fmaxf(D2b[t][rg], 0.f);
            }
            if (t < 2) {
                *(f16x4*)&s0buf2[px * 40 + t * 16 + q * 4] = h0;
                *(f16x4*)&s1buf2[px * 40 + t * 16 + q * 4] = h1;
            } else if (q == 0) {  // ch 32..35 only; ch>=36 don't exist
                *(f16x4*)&s0buf2[px * 40 + 32] = h0;
                *(f16x4*)&s1buf2[px * 40 + 32] = h1;
            }
        }
        const f16x8 B3a0 = *(const f16x8*)&s0buf2[px * 40 + q * 8];
        const f16x8 B3b0 = *(const f16x8*)&s1buf2[px * 40 + q * 8];
        f16x8 B3a1 = {0, 0, 0, 0, 0, 0, 0, 0};
        f16x8 B3b1 = {0, 0, 0, 0, 0, 0, 0, 0};
        if (q == 0) {  // k-slice2: j0..3 = ch32..35, j4 = bias channel (=1)
            const f16x4 t0 = *(const f16x4*)&s0buf2[px * 40 + 32];
            const f16x4 t1 = *(const f16x4*)&s1buf2[px * 40 + 32];
#pragma unroll
            for (int j = 0; j < 4; ++j) { B3a1[j] = t0[j]; B3b1[j] = t1[j]; }
            B3a1[4] = (_Float16)1.f;
            B3b1[4] = (_Float16)1.f;
        }

        // ---- layer 3 (two K-slices, bias via k=36) ----
        f32x4 D3a[3], D3b[3];
#pragma unroll
        for (int t = 0; t < 3; ++t) {
            D3a[t] = __builtin_amdgcn_mfma_f32_16x16x32_f16(A3s0[t], B3a0, zf4, 0, 0, 0);
            D3a[t] = __builtin_amdgcn_mfma_f32_16x16x32_f16(A3s1[t], B3a1, D3a[t], 0, 0, 0);
            D3b[t] = __builtin_amdgcn_mfma_f32_16x16x32_f16(A3s0[t], B3b0, zf4, 0, 0, 0);
            D3b[t] = __builtin_amdgcn_mfma_f32_16x16x32_f16(A3s1[t], B3b1, D3b[t], 0, 0, 0);
        }

        // ---- layer 4 epilogue (two independent shuffle chains) ----
        float sa = 0.f, sb = 0.f;
#pragma unroll
        for (int t = 0; t < 3; ++t)
#pragma unroll
            for (int rg = 0; rg < 4; ++rg) {
                sa = fmaf(w4r[t][rg], fmaxf(D3a[t][rg], 0.f), sa);
                sb = fmaf(w4r[t][rg], fmaxf(D3b[t][rg], 0.f), sb);
            }
        sa += __shfl_xor(sa, 16, 64); sb += __shfl_xor(sb, 16, 64);
        sa += __shfl_xor(sa, 32, 64); sb += __shfl_xor(sb, 32, 64);
        sa += b4s; sb += b4s;

        sa = colok ? sa : NEG_INF;
        sb = colok ? sb : NEG_INF;
        colmax = fmaxf(colmax, fmaxf(sa, sb));

        float m0 = sa, m1 = sb;
        m0 = fmaxf(m0, __shfl_xor(m0, 1, 64)); m1 = fmaxf(m1, __shfl_xor(m1, 1, 64));
        m0 = fmaxf(m0, __shfl_xor(m0, 2, 64)); m1 = fmaxf(m1, __shfl_xor(m1, 2, 64));
        m0 = fmaxf(m0, __shfl_xor(m0, 4, 64)); m1 = fmaxf(m1, __shfl_xor(m1, 4, 64));
        m0 = fmaxf(m0, __shfl_xor(m0, 8, 64)); m1 = fmaxf(m1, __shfl_xor(m1, 8, 64));
        if (tx == 0) {
            atomicMax(&rowbuck[r0], fenc(m0));
            atomicMax(&rowbuck[r1], fenc(m1));
        }
    }

    if (q == 0 && colok) atomicMax(&colbuck[col], fenc(colmax));
}

extern "C" void kernel_launch(void* const* d_in, const int* in_sizes, int n_in,
                              void* d_out, int out_size, void* d_ws, size_t ws_size,
                              hipStream_t stream) {
    const float* in = (const float*)d_in[0];
    // d_in[1] = T_out (unused), d_in[2] = T_indices (identity, unused)
    const float* w1 = (const float*)d_in[3];
    const float* b1 = (const float*)d_in[4];
    const float* w2 = (const float*)d_in[5];
    const float* b2 = (const float*)d_in[6];
    const float* w3 = (const float*)d_in[7];
    const float* b3 = (const float*)d_in[8];
    const float* w4 = (const float*)d_in[9];
    const float* b4 = (const float*)d_in[10];

    unsigned* buck = (unsigned*)d_out;  // [0,2000) row maxes, [2000,3000) col maxes

    init_buckets<<<(3000 + 255) / 256, 256, 0, stream>>>(buck, 3000);

    dim3 block(64, 4);
    dim3 grid(16, 125);  // 64 cols x 16 rows per block
    mlp_max_mfma<<<grid, block, 0, stream>>>(in, w1, b1, w2, b2, w3, b3, w4, b4,
                                             buck, buck + 2000);

    decode_buckets<<<(3000 + 255) / 256, 256, 0, stream>>>(buck, 3000);
}